// Round 6
// baseline (208.402 us; speedup 1.0000x reference)
//
#include <hip/hip_runtime.h>
#include <stdint.h>

#define UU 512
#define NHEAD 8
#define NB 8
#define NXX 1024
#define NYY 1024
#define SCALE_F 0.125f   // 1/sqrt(64)

typedef __bf16 bf16x8 __attribute__((ext_vector_type(8)));
typedef float f32x4 __attribute__((ext_vector_type(4)));
typedef unsigned short us4 __attribute__((ext_vector_type(4)));

__device__ __forceinline__ unsigned short f2bf(float f) {
  union { float f; uint32_t u; } v; v.f = f;
  return (unsigned short)((v.u + 0x7FFFu + ((v.u >> 16) & 1u)) >> 16);
}

// ---------------------------------------------------------------------------
// prep: blocks 0..1023 cast W->bf16; blocks 1024..1039 probe mask dtype.
// u8 bool -> nonzero bytes at p%4==1; i32/f32 -> zero there.
__global__ void prep_kernel(const float* __restrict__ W, unsigned short* __restrict__ Wb,
                            const unsigned char* __restrict__ m, int* __restrict__ det) {
  int blk = blockIdx.x, t = threadIdx.x;
  if (blk < 1024) {
    int i = blk * 256 + t;
    Wb[i] = f2bf(W[i]);
  } else {
    int idx = ((blk - 1024) * 256 + t) * 16;   // 16 blocks x 256 x 16B = 64KB
    uint4 v = *(const uint4*)(m + idx);
    unsigned int c1 = (v.x & 0xff00u) | (v.y & 0xff00u) | (v.z & 0xff00u) | (v.w & 0xff00u);
    if (c1) atomicOr(&det[0], 1);
  }
}

// ---------------------------------------------------------------------------
// cv[bz][n][u] = sum_i W[u][i] * src[b][i][n].
// Block = (bz, 32 n-rows, 256 u). x staged K-resident in LDS (transposed bf16,
// granule-XOR swizzle). W K-slice [256u][64k] staged per kt into LDS with
// XOR swizzle g' = g ^ (u&7); T14 split: issue W[kt+1] loads before compute,
// ds_write after the barrier. All MFMA operands come from LDS.
__global__ __launch_bounds__(256, 2) void conv_fused(
    const float* __restrict__ x, const float* __restrict__ y,
    const unsigned short* __restrict__ Wb, unsigned short* __restrict__ cv) {
  __shared__ unsigned short xs[32 * 512];    // 32 KB
  __shared__ unsigned short wsld[256 * 64];  // 32 KB
  int fl = blockIdx.x;
  int bz = fl & 15, nt = (fl >> 4) & 31, ut = fl >> 9;
  int b = bz & 7;
  const float* src = (bz >> 3) ? y : x;
  int n0 = nt * 32;
  int t = threadIdx.x, w = t >> 6, l = t & 63;
  int lane_m = l & 15, lane_g = l >> 4;

  // ---- stage x K-resident: [32n][512k] bf16, pair-packed, granule swizzle
  {
    int cq = (t & 7) * 4;
    int i2b = (t >> 3) * 2;
    const float* gb = src + (size_t)b * UU * NXX + n0 + cq;
#pragma unroll
    for (int it = 0; it < 8; it++) {
      int i2 = i2b + it * 64;
      float4 va = *(const float4*)(gb + (size_t)i2 * NXX);
      float4 vb = *(const float4*)(gb + (size_t)(i2 + 1) * NXX);
#pragma unroll
      for (int j = 0; j < 4; j++) {
        int n = cq + j;
        unsigned int pk = (unsigned int)f2bf(((const float*)&va)[j])
                        | ((unsigned int)f2bf(((const float*)&vb)[j]) << 16);
        int e = n * 512 + (i2 ^ ((n & 7) << 3));
        *(unsigned int*)&xs[e] = pk;
      }
    }
  }

  // ---- W staging geometry: wave w handles chunks j*4+w (8u x 64k each kt)
  // lane l: u_loc = chunk*8 + (l>>3), reads src granule (l&7), writes slot
  // g' = (l&7) ^ (u&7)  -> both write and frag-read are <=2 lanes/bank.
  int u_l[8], gsl[8];
#pragma unroll
  for (int j = 0; j < 8; j++) {
    int chunk = j * 4 + w;
    u_l[j] = chunk * 8 + (l >> 3);
    gsl[j] = (l & 7) ^ (u_l[j] & 7);
  }
  const unsigned short* wsrc = Wb + (size_t)ut * 256 * UU + (l & 7) * 8;
  uint4 wreg[8];

#define ISSUEW(KT) do {                                                       \
    _Pragma("unroll") for (int j = 0; j < 8; j++)                             \
      wreg[j] = *(const uint4*)(wsrc + (size_t)u_l[j] * UU + (KT) * 64);      \
  } while (0)
#define WRITEW() do {                                                         \
    _Pragma("unroll") for (int j = 0; j < 8; j++)                             \
      *(uint4*)&wsld[u_l[j] * 64 + gsl[j] * 8] = wreg[j];                     \
  } while (0)

  f32x4 acc[2][4] = {};
  ISSUEW(0);
  WRITEW();
  __syncthreads();   // xs + wsld[0] ready

  for (int kt = 0; kt < 8; kt++) {
    if (kt < 7) ISSUEW(kt + 1);            // L2 loads in flight during compute
    bf16x8 af[2][4], bff[2][2];
#pragma unroll
    for (int kb = 0; kb < 2; kb++) {
#pragma unroll
      for (int tu = 0; tu < 4; tu++) {
        int ur = w * 64 + tu * 16 + lane_m;
        int gp = ((kb * 4 + lane_g) ^ (ur & 7)) * 8;
        af[kb][tu] = *(const bf16x8*)&wsld[ur * 64 + gp];
      }
#pragma unroll
      for (int tn = 0; tn < 2; tn++) {
        int nl = tn * 16 + lane_m;
        int ka = kt * 64 + kb * 32 + lane_g * 8;
        bff[kb][tn] = *(const bf16x8*)&xs[nl * 512 + (ka ^ ((nl & 7) << 3))];
      }
    }
#pragma unroll
    for (int kb = 0; kb < 2; kb++)
#pragma unroll
      for (int tn = 0; tn < 2; tn++)
#pragma unroll
        for (int tu = 0; tu < 4; tu++)
          acc[tn][tu] = __builtin_amdgcn_mfma_f32_16x16x32_bf16(af[kb][tu], bff[kb][tn], acc[tn][tu], 0, 0, 0);
    __syncthreads();                       // all waves done reading wsld[kt]
    if (kt < 7) {
      WRITEW();
      __syncthreads();
    }
  }
#undef ISSUEW
#undef WRITEW

  unsigned short* ob = cv + (size_t)bz * NXX * UU;
#pragma unroll
  for (int tn = 0; tn < 2; tn++)
#pragma unroll
    for (int tu = 0; tu < 4; tu++) {
      int n = n0 + tn * 16 + lane_m;
      int u = ut * 256 + w * 64 + tu * 16 + 4 * lane_g;
      us4 pk;
      pk.x = f2bf(acc[tn][tu][0]); pk.y = f2bf(acc[tn][tu][1]);
      pk.z = f2bf(acc[tn][tu][2]); pk.w = f2bf(acc[tn][tu][3]);
      *(us4*)(ob + (size_t)n * UU + u) = pk;
    }
}

// ---------------------------------------------------------------------------
// Block: (b, 64n, 64m), all 8 heads, 4 waves. x-frags hoisted to regs (issued
// first), y-tile 64x512 staged to LDS coalesced w/ granule-XOR swizzle, mask
// staged as bf16. Inner loop per head: 8 ds_read_b128 + 16 MFMA.
__global__ __launch_bounds__(256, 2) void score_kernel(
    const unsigned short* __restrict__ cv, const void* __restrict__ maskp,
    const int* __restrict__ det, float* __restrict__ part) {
  __shared__ unsigned short ys[64 * 512];    // 64 KB
  __shared__ unsigned short mf16[64][72];    // 9.2 KB bf16 0/1
  __shared__ float red[4][8];
  int fl = blockIdx.x;
  int b = fl & 7, rr = fl >> 3;
  int nt = rr & 15, mt = rr >> 4;
  int t = threadIdx.x, w = t >> 6, l = t & 63;
  int lane_m = l & 15, lane_g = l >> 4;
  int n0 = nt * 64, m0 = mt * 64;
  int nw0 = (w & 1) * 32, hq = (w >> 1) * 4;

  // ---- x-side frags for all 4 heads: issue before staging (latency hidden)
  const unsigned short* xb = cv + ((size_t)b * NXX + n0 + nw0) * UU;
  bf16x8 afr[4][2][2];
#pragma unroll
  for (int hh = 0; hh < 4; hh++) {
    int co = (hq + hh) * 64;
#pragma unroll
    for (int tn = 0; tn < 2; tn++)
#pragma unroll
      for (int kb = 0; kb < 2; kb++)
        afr[hh][tn][kb] = *(const bf16x8*)(xb + (size_t)(tn * 16 + lane_m) * UU + co + kb * 32 + lane_g * 8);
  }

  // ---- stage y tile (64 rows x 512) into LDS, granule-XOR swizzle
  const unsigned short* yb = cv + ((size_t)(NB + b) * NYY + m0) * UU;
  {
    int seg = t & 63;
#pragma unroll
    for (int p = 0; p < 16; p++) {
      int r2 = p * 4 + (t >> 6);
      uint4 v = *(const uint4*)(yb + (size_t)r2 * UU + seg * 8);
      int sp = seg ^ (r2 & 7);
      *(uint4*)&ys[r2 * 512 + sp * 8] = v;
    }
  }

  // ---- mask -> mf16 (bf16 0/1) + count
  int is_u8 = det[0] != 0;
  unsigned int cl = 0;
  {
    int row = t >> 2, cq = (t & 3) * 16;
    size_t eb = ((size_t)b * NXX + n0 + row) * NYY + m0 + cq;
    if (is_u8) {
      uint4 v = *(const uint4*)((const unsigned char*)maskp + eb);
#pragma unroll
      for (int j = 0; j < 16; j++) {
        unsigned int word = ((const unsigned int*)&v)[j >> 2];
        int bit = ((word >> ((j & 3) * 8)) & 0xffu) != 0;
        mf16[row][cq + j] = bit ? 0x3F80u : 0u;
        cl += (unsigned)bit;
      }
    } else {
      const unsigned int* mp = (const unsigned int*)maskp + eb;
#pragma unroll
      for (int q = 0; q < 4; q++) {
        uint4 v = *(const uint4*)(mp + q * 4);
        unsigned int wds[4] = {v.x, v.y, v.z, v.w};
#pragma unroll
        for (int j = 0; j < 4; j++) {
          int bit = wds[j] != 0;
          mf16[row][cq + q * 4 + j] = bit ? 0x3F80u : 0u;
          cl += (unsigned)bit;
        }
      }
    }
  }
  for (int s = 1; s < 64; s <<= 1) cl += __shfl_xor(cl, s);
  if (l == 0) red[w][4] = (float)cl;
  __syncthreads();

  // ---- mask frags to regs (2-way LDS aliasing only)
  float mreg[2][4][4];
#pragma unroll
  for (int tn = 0; tn < 2; tn++)
#pragma unroll
    for (int tm = 0; tm < 4; tm++)
#pragma unroll
      for (int r = 0; r < 4; r++) {
        unsigned int u = (unsigned int)mf16[nw0 + tn * 16 + 4 * lane_g + r][tm * 16 + lane_m] << 16;
        union { unsigned int u; float f; } cvt; cvt.u = u;
        mreg[tn][tm][r] = cvt.f;
      }

  // ---- per-head: y frags from LDS, MFMA, fused relu*mask accumulate
  float hsv[4] = {0.f, 0.f, 0.f, 0.f};
#pragma unroll
  for (int hh = 0; hh < 4; hh++) {
    int segbase = (hq + hh) * 8;            // head chunk = 8 granules
    bf16x8 bfr[4][2];
#pragma unroll
    for (int tm = 0; tm < 4; tm++) {
      int row = tm * 16 + lane_m;
#pragma unroll
      for (int kb = 0; kb < 2; kb++) {
        int sp = (segbase + kb * 4 + lane_g) ^ (row & 7);
        bfr[tm][kb] = *(const bf16x8*)&ys[row * 512 + sp * 8];
      }
    }
#pragma unroll
    for (int tn = 0; tn < 2; tn++)
#pragma unroll
      for (int tm = 0; tm < 4; tm++) {
        f32x4 acc = {};
        acc = __builtin_amdgcn_mfma_f32_16x16x32_bf16(afr[hh][tn][0], bfr[tm][0], acc, 0, 0, 0);
        acc = __builtin_amdgcn_mfma_f32_16x16x32_bf16(afr[hh][tn][1], bfr[tm][1], acc, 0, 0, 0);
#pragma unroll
        for (int r = 0; r < 4; r++) {
          float v = acc[r];
          v = v > 0.f ? v : 0.f;
          hsv[hh] = fmaf(v, mreg[tn][tm][r], hsv[hh]);
        }
      }
  }
#pragma unroll
  for (int hh = 0; hh < 4; hh++) {
    float hs = hsv[hh];
    for (int s = 1; s < 64; s <<= 1) hs += __shfl_xor(hs, s);
    if (l == 0) red[w][hh] = hs;
  }
  __syncthreads();
  float* pb = part + (size_t)fl * 16;
  if (t < 8) {
    int q = t >> 2, hh = t & 3;
    pb[t] = red[q * 2][hh] + red[q * 2 + 1][hh];
  } else if (t == 8) {
    pb[8] = red[0][4] + red[1][4] + red[2][4] + red[3][4];
  }
}

// ---------------------------------------------------------------------------
// One block per b. Batch b's score blocks are fl = j*8 + b (fl&7==b), j=0..255.
__global__ __launch_bounds__(256) void finalize(
    const float* __restrict__ part, const float* __restrict__ fcw,
    const float* __restrict__ fcb, float* __restrict__ out) {
  __shared__ float red[4][9];
  int b = blockIdx.x;
  int t = threadIdx.x, w = t >> 6, l = t & 63;
  const float* pb = part + (size_t)(t * 8 + b) * 16;   // row fl = t*8+b
  float v[9];
#pragma unroll
  for (int j = 0; j < 9; j++) v[j] = pb[j];
#pragma unroll
  for (int j = 0; j < 9; j++) {
    float s = v[j];
    for (int ss = 1; ss < 64; ss <<= 1) s += __shfl_xor(s, ss);
    v[j] = s;
  }
  if (l == 0)
#pragma unroll
    for (int j = 0; j < 9; j++) red[w][j] = v[j];
  __syncthreads();
  if (t == 0) {
    float s = 0.f, cn = 0.f;
#pragma unroll
    for (int h = 0; h < NHEAD; h++)
      s += (red[0][h] + red[1][h] + red[2][h] + red[3][h]) * fcw[h];
    cn = red[0][8] + red[1][8] + red[2][8] + red[3][8];
    if (cn < 0.5f) cn = 1.f;
    out[b] = s * (SCALE_F / cn) + fcb[0];
  }
}

// ---------------------------------------------------------------------------
extern "C" void kernel_launch(void* const* d_in, const int* in_sizes, int n_in,
                              void* d_out, int out_size, void* d_ws, size_t ws_size,
                              hipStream_t stream) {
  const float* x = (const float*)d_in[0];
  const float* y = (const float*)d_in[1];
  const void* mask = d_in[2];
  const float* W = (const float*)d_in[3];
  const float* fcw = (const float*)d_in[4];
  const float* fcb = (const float*)d_in[5];
  float* out = (float*)d_out;
  char* ws = (char*)d_ws;

  unsigned short* cv = (unsigned short*)ws;                  // [16][1024][512] bf16 = 16 MB
  unsigned short* Wb = (unsigned short*)(ws + (16u << 20));  // [512][512] bf16 = 512 KB
  float* part = (float*)(ws + (16u << 20) + (1u << 19));     // [2048][16] f32 = 128 KB
  char* st = ws + (16u << 20) + (1u << 19) + (1u << 17);
  int* det = (int*)st;                                        // 1 i32

  hipMemsetAsync(st, 0, 64, stream);
  prep_kernel<<<1040, 256, 0, stream>>>(W, Wb, (const unsigned char*)mask, det);
  conv_fused<<<1024, 256, 0, stream>>>(x, y, Wb, cv);
  score_kernel<<<2048, 256, 0, stream>>>(cv, mask, det, part);
  finalize<<<NB, 256, 0, stream>>>(part, fcw, fcb, out);
}

// Round 7
// 166.910 us; speedup vs baseline: 1.2486x; 1.2486x over previous
//
#include <hip/hip_runtime.h>
#include <stdint.h>

#define UU 512
#define NHEAD 8
#define NB 8
#define NXX 1024
#define NYY 1024
#define SCALE_F 0.125f   // 1/sqrt(64)

typedef __bf16 bf16x8 __attribute__((ext_vector_type(8)));
typedef float f32x4 __attribute__((ext_vector_type(4)));
typedef unsigned short us4 __attribute__((ext_vector_type(4)));

__device__ __forceinline__ unsigned short f2bf(float f) {
  union { float f; uint32_t u; } v; v.f = f;
  return (unsigned short)((v.u + 0x7FFFu + ((v.u >> 16) & 1u)) >> 16);
}

// ---------------------------------------------------------------------------
// prep: blocks 0..1023 cast W->bf16; blocks 1024..1039 probe mask dtype.
// u8 bool -> nonzero bytes at p%4==1; i32/f32 -> zero there.
__global__ void prep_kernel(const float* __restrict__ W, unsigned short* __restrict__ Wb,
                            const unsigned char* __restrict__ m, int* __restrict__ det) {
  int blk = blockIdx.x, t = threadIdx.x;
  if (blk < 1024) {
    int i = blk * 256 + t;
    Wb[i] = f2bf(W[i]);
  } else {
    int idx = ((blk - 1024) * 256 + t) * 16;   // 16 blocks x 256 x 16B = 64KB
    uint4 v = *(const uint4*)(m + idx);
    unsigned int c1 = (v.x & 0xff00u) | (v.y & 0xff00u) | (v.z & 0xff00u) | (v.w & 0xff00u);
    if (c1) atomicOr(&det[0], 1);
  }
}

// ---------------------------------------------------------------------------
// cv[bz][n][u] = sum_i W[u][i] * src[b][i][n].
// R5 dataflow (W frags from global/L2, x from swizzled LDS, no inner barriers)
// with u-split: block = (bz, 32 n-rows, 256 u), grid 1024 -> 4 blocks/CU.
// Wave w owns 64 u rows; acc[2][4] (32 VGPR); 2-deep explicit kb pipeline.
__global__ __launch_bounds__(256, 4) void conv_fused(
    const float* __restrict__ x, const float* __restrict__ y,
    const unsigned short* __restrict__ Wb, unsigned short* __restrict__ cv) {
  __shared__ unsigned short xs[32 * 512];    // 32 KB
  int fl = blockIdx.x;
  int bz = fl & 15, nt = (fl >> 4) & 31, ut = fl >> 9;
  int b = bz & 7;
  const float* src = (bz >> 3) ? y : x;
  int n0 = nt * 32;
  int t = threadIdx.x, w = t >> 6, l = t & 63;
  int lane_m = l & 15, lane_g = l >> 4;

  // ---- stage x K-resident: [32n][512k] bf16, pair-packed, granule swizzle
  {
    int cq = (t & 7) * 4;
    int i2b = (t >> 3) * 2;
    const float* gb = src + (size_t)b * UU * NXX + n0 + cq;
#pragma unroll
    for (int it = 0; it < 8; it++) {
      int i2 = i2b + it * 64;
      float4 va = *(const float4*)(gb + (size_t)i2 * NXX);
      float4 vb = *(const float4*)(gb + (size_t)(i2 + 1) * NXX);
#pragma unroll
      for (int j = 0; j < 4; j++) {
        int n = cq + j;
        unsigned int pk = (unsigned int)f2bf(((const float*)&va)[j])
                        | ((unsigned int)f2bf(((const float*)&vb)[j]) << 16);
        int e = n * 512 + (i2 ^ ((n & 7) << 3));
        *(unsigned int*)&xs[e] = pk;
      }
    }
  }
  __syncthreads();

  int u0 = ut * 256 + w * 64;
  const unsigned short* wb0 = Wb + (size_t)u0 * UU;
  f32x4 acc[2][4] = {};
  bf16x8 aA[4], aB[4], bA[2], bB[2];

#define LOADW(Adst, Bdst, KB) do {                                            \
    int k_ = (KB) * 32 + lane_g * 8;                                          \
    _Pragma("unroll") for (int tu = 0; tu < 4; tu++)                          \
      Adst[tu] = *(const bf16x8*)(wb0 + (size_t)(tu * 16 + lane_m) * UU + k_);\
    _Pragma("unroll") for (int tn = 0; tn < 2; tn++) {                        \
      int nl_ = tn * 16 + lane_m;                                             \
      Bdst[tn] = *(const bf16x8*)&xs[nl_ * 512 + (k_ ^ ((nl_ & 7) << 3))];    \
    }                                                                         \
  } while (0)
#define DOMFMA(Ab, Bb) do {                                                   \
    _Pragma("unroll") for (int tn = 0; tn < 2; tn++)                          \
    _Pragma("unroll") for (int tu = 0; tu < 4; tu++)                          \
      acc[tn][tu] = __builtin_amdgcn_mfma_f32_16x16x32_bf16(Ab[tu], Bb[tn], acc[tn][tu], 0, 0, 0); \
  } while (0)

  LOADW(aA, bA, 0);
#pragma unroll
  for (int kp = 0; kp < 8; kp++) {
    LOADW(aB, bB, 2 * kp + 1);
    DOMFMA(aA, bA);
    if (kp < 7) LOADW(aA, bA, 2 * kp + 2);
    DOMFMA(aB, bB);
  }
#undef LOADW
#undef DOMFMA

  unsigned short* ob = cv + (size_t)bz * NXX * UU;
#pragma unroll
  for (int tn = 0; tn < 2; tn++)
#pragma unroll
    for (int tu = 0; tu < 4; tu++) {
      int n = n0 + tn * 16 + lane_m;
      int u = u0 + tu * 16 + 4 * lane_g;
      us4 pk;
      pk.x = f2bf(acc[tn][tu][0]); pk.y = f2bf(acc[tn][tu][1]);
      pk.z = f2bf(acc[tn][tu][2]); pk.w = f2bf(acc[tn][tu][3]);
      *(us4*)(ob + (size_t)n * UU + u) = pk;
    }
}

// ---------------------------------------------------------------------------
// Block: (b, 64n, 64m), all 8 heads, 4 waves. x-frags hoisted to regs (issued
// first), y-tile 64x512 staged to LDS coalesced w/ granule-XOR swizzle, mask
// staged as bf16. Inner loop per head: 8 ds_read_b128 + 16 MFMA.
__global__ __launch_bounds__(256, 2) void score_kernel(
    const unsigned short* __restrict__ cv, const void* __restrict__ maskp,
    const int* __restrict__ det, float* __restrict__ part) {
  __shared__ unsigned short ys[64 * 512];    // 64 KB
  __shared__ unsigned short mf16[64][72];    // 9.2 KB bf16 0/1
  __shared__ float red[4][8];
  int fl = blockIdx.x;
  int b = fl & 7, rr = fl >> 3;
  int nt = rr & 15, mt = rr >> 4;
  int t = threadIdx.x, w = t >> 6, l = t & 63;
  int lane_m = l & 15, lane_g = l >> 4;
  int n0 = nt * 64, m0 = mt * 64;
  int nw0 = (w & 1) * 32, hq = (w >> 1) * 4;

  // ---- x-side frags for all 4 heads: issue before staging (latency hidden)
  const unsigned short* xb = cv + ((size_t)b * NXX + n0 + nw0) * UU;
  bf16x8 afr[4][2][2];
#pragma unroll
  for (int hh = 0; hh < 4; hh++) {
    int co = (hq + hh) * 64;
#pragma unroll
    for (int tn = 0; tn < 2; tn++)
#pragma unroll
      for (int kb = 0; kb < 2; kb++)
        afr[hh][tn][kb] = *(const bf16x8*)(xb + (size_t)(tn * 16 + lane_m) * UU + co + kb * 32 + lane_g * 8);
  }

  // ---- stage y tile (64 rows x 512) into LDS, granule-XOR swizzle
  const unsigned short* yb = cv + ((size_t)(NB + b) * NYY + m0) * UU;
  {
    int seg = t & 63;
#pragma unroll
    for (int p = 0; p < 16; p++) {
      int r2 = p * 4 + (t >> 6);
      uint4 v = *(const uint4*)(yb + (size_t)r2 * UU + seg * 8);
      int sp = seg ^ (r2 & 7);
      *(uint4*)&ys[r2 * 512 + sp * 8] = v;
    }
  }

  // ---- mask -> mf16 (bf16 0/1) + count
  int is_u8 = det[0] != 0;
  unsigned int cl = 0;
  {
    int row = t >> 2, cq = (t & 3) * 16;
    size_t eb = ((size_t)b * NXX + n0 + row) * NYY + m0 + cq;
    if (is_u8) {
      uint4 v = *(const uint4*)((const unsigned char*)maskp + eb);
#pragma unroll
      for (int j = 0; j < 16; j++) {
        unsigned int word = ((const unsigned int*)&v)[j >> 2];
        int bit = ((word >> ((j & 3) * 8)) & 0xffu) != 0;
        mf16[row][cq + j] = bit ? 0x3F80u : 0u;
        cl += (unsigned)bit;
      }
    } else {
      const unsigned int* mp = (const unsigned int*)maskp + eb;
#pragma unroll
      for (int q = 0; q < 4; q++) {
        uint4 v = *(const uint4*)(mp + q * 4);
        unsigned int wds[4] = {v.x, v.y, v.z, v.w};
#pragma unroll
        for (int j = 0; j < 4; j++) {
          int bit = wds[j] != 0;
          mf16[row][cq + q * 4 + j] = bit ? 0x3F80u : 0u;
          cl += (unsigned)bit;
        }
      }
    }
  }
  for (int s = 1; s < 64; s <<= 1) cl += __shfl_xor(cl, s);
  if (l == 0) red[w][4] = (float)cl;
  __syncthreads();

  // ---- mask frags to regs (2-way LDS aliasing only)
  float mreg[2][4][4];
#pragma unroll
  for (int tn = 0; tn < 2; tn++)
#pragma unroll
    for (int tm = 0; tm < 4; tm++)
#pragma unroll
      for (int r = 0; r < 4; r++) {
        unsigned int u = (unsigned int)mf16[nw0 + tn * 16 + 4 * lane_g + r][tm * 16 + lane_m] << 16;
        union { unsigned int u; float f; } cvt; cvt.u = u;
        mreg[tn][tm][r] = cvt.f;
      }

  // ---- per-head: y frags from LDS, MFMA, fused relu*mask accumulate
  float hsv[4] = {0.f, 0.f, 0.f, 0.f};
#pragma unroll
  for (int hh = 0; hh < 4; hh++) {
    int segbase = (hq + hh) * 8;            // head chunk = 8 granules
    bf16x8 bfr[4][2];
#pragma unroll
    for (int tm = 0; tm < 4; tm++) {
      int row = tm * 16 + lane_m;
#pragma unroll
      for (int kb = 0; kb < 2; kb++) {
        int sp = (segbase + kb * 4 + lane_g) ^ (row & 7);
        bfr[tm][kb] = *(const bf16x8*)&ys[row * 512 + sp * 8];
      }
    }
#pragma unroll
    for (int tn = 0; tn < 2; tn++)
#pragma unroll
      for (int tm = 0; tm < 4; tm++) {
        f32x4 acc = {};
        acc = __builtin_amdgcn_mfma_f32_16x16x32_bf16(afr[hh][tn][0], bfr[tm][0], acc, 0, 0, 0);
        acc = __builtin_amdgcn_mfma_f32_16x16x32_bf16(afr[hh][tn][1], bfr[tm][1], acc, 0, 0, 0);
#pragma unroll
        for (int r = 0; r < 4; r++) {
          float v = acc[r];
          v = v > 0.f ? v : 0.f;
          hsv[hh] = fmaf(v, mreg[tn][tm][r], hsv[hh]);
        }
      }
  }
#pragma unroll
  for (int hh = 0; hh < 4; hh++) {
    float hs = hsv[hh];
    for (int s = 1; s < 64; s <<= 1) hs += __shfl_xor(hs, s);
    if (l == 0) red[w][hh] = hs;
  }
  __syncthreads();
  float* pb = part + (size_t)fl * 16;
  if (t < 8) {
    int q = t >> 2, hh = t & 3;
    pb[t] = red[q * 2][hh] + red[q * 2 + 1][hh];
  } else if (t == 8) {
    pb[8] = red[0][4] + red[1][4] + red[2][4] + red[3][4];
  }
}

// ---------------------------------------------------------------------------
// One block per b. Batch b's score blocks are fl = j*8 + b (fl&7==b), j=0..255.
__global__ __launch_bounds__(256) void finalize(
    const float* __restrict__ part, const float* __restrict__ fcw,
    const float* __restrict__ fcb, float* __restrict__ out) {
  __shared__ float red[4][9];
  int b = blockIdx.x;
  int t = threadIdx.x, w = t >> 6, l = t & 63;
  const float* pb = part + (size_t)(t * 8 + b) * 16;   // row fl = t*8+b
  float v[9];
#pragma unroll
  for (int j = 0; j < 9; j++) v[j] = pb[j];
#pragma unroll
  for (int j = 0; j < 9; j++) {
    float s = v[j];
    for (int ss = 1; ss < 64; ss <<= 1) s += __shfl_xor(s, ss);
    v[j] = s;
  }
  if (l == 0)
#pragma unroll
    for (int j = 0; j < 9; j++) red[w][j] = v[j];
  __syncthreads();
  if (t == 0) {
    float s = 0.f, cn = 0.f;
#pragma unroll
    for (int h = 0; h < NHEAD; h++)
      s += (red[0][h] + red[1][h] + red[2][h] + red[3][h]) * fcw[h];
    cn = red[0][8] + red[1][8] + red[2][8] + red[3][8];
    if (cn < 0.5f) cn = 1.f;
    out[b] = s * (SCALE_F / cn) + fcb[0];
  }
}

// ---------------------------------------------------------------------------
extern "C" void kernel_launch(void* const* d_in, const int* in_sizes, int n_in,
                              void* d_out, int out_size, void* d_ws, size_t ws_size,
                              hipStream_t stream) {
  const float* x = (const float*)d_in[0];
  const float* y = (const float*)d_in[1];
  const void* mask = d_in[2];
  const float* W = (const float*)d_in[3];
  const float* fcw = (const float*)d_in[4];
  const float* fcb = (const float*)d_in[5];
  float* out = (float*)d_out;
  char* ws = (char*)d_ws;

  unsigned short* cv = (unsigned short*)ws;                  // [16][1024][512] bf16 = 16 MB
  unsigned short* Wb = (unsigned short*)(ws + (16u << 20));  // [512][512] bf16 = 512 KB
  float* part = (float*)(ws + (16u << 20) + (1u << 19));     // [2048][16] f32 = 128 KB
  char* st = ws + (16u << 20) + (1u << 19) + (1u << 17);
  int* det = (int*)st;                                        // 1 i32

  hipMemsetAsync(st, 0, 64, stream);
  prep_kernel<<<1040, 256, 0, stream>>>(W, Wb, (const unsigned char*)mask, det);
  conv_fused<<<1024, 256, 0, stream>>>(x, y, Wb, cv);
  score_kernel<<<2048, 256, 0, stream>>>(cv, mask, det, part);
  finalize<<<NB, 256, 0, stream>>>(part, fcw, fcb, out);
}

// Round 8
// 144.284 us; speedup vs baseline: 1.4444x; 1.1568x over previous
//
#include <hip/hip_runtime.h>
#include <stdint.h>

#define UU 512
#define NHEAD 8
#define NB 8
#define NXX 1024
#define NYY 1024
#define SCALE_F 0.125f   // 1/sqrt(64)

typedef __bf16 bf16x8 __attribute__((ext_vector_type(8)));
typedef float f32x4 __attribute__((ext_vector_type(4)));
typedef unsigned short us4 __attribute__((ext_vector_type(4)));

__device__ __forceinline__ unsigned short f2bf(float f) {
  union { float f; uint32_t u; } v; v.f = f;
  return (unsigned short)((v.u + 0x7FFFu + ((v.u >> 16) & 1u)) >> 16);
}

// ---------------------------------------------------------------------------
// prep: blocks 0..127 pack W -> bf16 fragment-order Wp[ub][kb][lane][8]:
//   slot s = (ub*16+kb)*64 + l ; u = ub*16 + (l&15) ; k = kb*32 + (l>>4)*8.
// A conv W-frag load = Wp + s*8 .. one contiguous 1024B wave-load.
// Blocks 128..143: mask dtype probe (u8 bool -> nonzero bytes at p%4==1).
__global__ void prep_kernel(const float* __restrict__ W, unsigned short* __restrict__ Wp,
                            const unsigned char* __restrict__ m, int* __restrict__ det) {
  int blk = blockIdx.x, t = threadIdx.x;
  if (blk < 128) {
    int s = blk * 256 + t;
    int ub = s >> 10, kb = (s >> 6) & 15, l = s & 63;
    int u = ub * 16 + (l & 15), k = kb * 32 + (l >> 4) * 8;
    const float* src = W + (size_t)u * UU + k;
    float4 a = *(const float4*)src;
    float4 bq = *(const float4*)(src + 4);
    uint4 o;
    o.x = (unsigned)f2bf(a.x) | ((unsigned)f2bf(a.y) << 16);
    o.y = (unsigned)f2bf(a.z) | ((unsigned)f2bf(a.w) << 16);
    o.z = (unsigned)f2bf(bq.x) | ((unsigned)f2bf(bq.y) << 16);
    o.w = (unsigned)f2bf(bq.z) | ((unsigned)f2bf(bq.w) << 16);
    *(uint4*)(Wp + (size_t)s * 8) = o;
  } else {
    int idx = ((blk - 128) * 256 + t) * 16;   // 16 blocks x 256 x 16B = 64KB
    uint4 v = *(const uint4*)(m + idx);
    unsigned int c1 = (v.x & 0xff00u) | (v.y & 0xff00u) | (v.z & 0xff00u) | (v.w & 0xff00u);
    if (c1) atomicOr(&det[0], 1);
  }
}

// ---------------------------------------------------------------------------
// cv[bz][n][u] = sum_i W[u][i] * src[b][i][n].
// Block = (bz, 64 n-rows, 256 u), grid 512 (2 blocks/CU). x staged K-resident
// in LDS (transposed bf16, granule-XOR swizzle), staged ONCE, no inner
// barriers. W frags from packed Wp (contiguous 1KB wave-loads). Wave tile
// 64u x 64n: per kb 4 W-loads + 4 ds_reads -> 16 MFMA. 2-deep kb pipeline.
__global__ __launch_bounds__(256, 2) void conv_fused(
    const float* __restrict__ x, const float* __restrict__ y,
    const unsigned short* __restrict__ Wp, unsigned short* __restrict__ cv) {
  __shared__ unsigned short xs[64 * 512];    // 64 KB
  int fl = blockIdx.x;
  int bz = fl & 15, nt = (fl >> 4) & 15, ut = fl >> 8;
  int b = bz & 7;
  const float* src = (bz >> 3) ? y : x;
  int n0 = nt * 64;
  int t = threadIdx.x, w = t >> 6, l = t & 63;
  int lane_m = l & 15, lane_g = l >> 4;

  // ---- stage x: [64n][512k] bf16, pair-packed along k, granule swizzle
  {
    int cq = (t & 15) * 4;
    int i2b = (t >> 4) * 2;
    const float* gb = src + (size_t)b * UU * NXX + n0 + cq;
#pragma unroll
    for (int it = 0; it < 16; it++) {
      int i2 = i2b + it * 32;
      float4 va = *(const float4*)(gb + (size_t)i2 * NXX);
      float4 vb = *(const float4*)(gb + (size_t)(i2 + 1) * NXX);
      float fa[4] = {va.x, va.y, va.z, va.w};
      float fb[4] = {vb.x, vb.y, vb.z, vb.w};
#pragma unroll
      for (int j = 0; j < 4; j++) {
        int n = cq + j;
        unsigned int pk = (unsigned)f2bf(fa[j]) | ((unsigned)f2bf(fb[j]) << 16);
        int e = n * 512 + (i2 ^ ((n & 7) << 3));
        *(unsigned int*)&xs[e] = pk;
      }
    }
  }
  __syncthreads();

  int u0 = ut * 256 + w * 64;
  int ub0 = u0 >> 4;                         // 16-row u-tile index base
  const unsigned short* wb0 = Wp + (size_t)l * 8;
  f32x4 acc[4][4] = {};
  bf16x8 aA[4], aB[4], bA[4], bB[4];

#define LOADW(Adst, Bdst, KB) do {                                            \
    _Pragma("unroll") for (int tu = 0; tu < 4; tu++)                          \
      Adst[tu] = *(const bf16x8*)(wb0 + ((size_t)(ub0 + tu) * 16 + (KB)) * 512); \
    _Pragma("unroll") for (int tn = 0; tn < 4; tn++) {                        \
      int nl_ = tn * 16 + lane_m;                                             \
      int ka_ = (KB) * 32 + lane_g * 8;                                       \
      Bdst[tn] = *(const bf16x8*)&xs[nl_ * 512 + (ka_ ^ ((nl_ & 7) << 3))];   \
    }                                                                         \
  } while (0)
#define DOMFMA(Ab, Bb) do {                                                   \
    _Pragma("unroll") for (int tn = 0; tn < 4; tn++)                          \
    _Pragma("unroll") for (int tu = 0; tu < 4; tu++)                          \
      acc[tn][tu] = __builtin_amdgcn_mfma_f32_16x16x32_bf16(Ab[tu], Bb[tn], acc[tn][tu], 0, 0, 0); \
  } while (0)

  LOADW(aA, bA, 0);
#pragma unroll
  for (int kp = 0; kp < 8; kp++) {
    LOADW(aB, bB, 2 * kp + 1);
    DOMFMA(aA, bA);
    if (kp < 7) LOADW(aA, bA, 2 * kp + 2);
    DOMFMA(aB, bB);
  }
#undef LOADW
#undef DOMFMA

  unsigned short* ob = cv + (size_t)bz * NXX * UU;
#pragma unroll
  for (int tn = 0; tn < 4; tn++)
#pragma unroll
    for (int tu = 0; tu < 4; tu++) {
      int n = n0 + tn * 16 + lane_m;
      int u = u0 + tu * 16 + 4 * lane_g;
      us4 pk;
      pk.x = f2bf(acc[tn][tu][0]); pk.y = f2bf(acc[tn][tu][1]);
      pk.z = f2bf(acc[tn][tu][2]); pk.w = f2bf(acc[tn][tu][3]);
      *(us4*)(ob + (size_t)n * UU + u) = pk;
    }
}

// ---------------------------------------------------------------------------
// Block: (b, 64n, 64m), all 8 heads, 4 waves. x-frags hoisted to regs (issued
// first), y-tile 64x512 staged to LDS coalesced w/ granule-XOR swizzle, mask
// staged as bf16. Inner loop per head: 8 ds_read_b128 + 16 MFMA.
__global__ __launch_bounds__(256, 2) void score_kernel(
    const unsigned short* __restrict__ cv, const void* __restrict__ maskp,
    const int* __restrict__ det, float* __restrict__ part) {
  __shared__ unsigned short ys[64 * 512];    // 64 KB
  __shared__ unsigned short mf16[64][72];    // 9.2 KB bf16 0/1
  __shared__ float red[4][8];
  int fl = blockIdx.x;
  int b = fl & 7, rr = fl >> 3;
  int nt = rr & 15, mt = rr >> 4;
  int t = threadIdx.x, w = t >> 6, l = t & 63;
  int lane_m = l & 15, lane_g = l >> 4;
  int n0 = nt * 64, m0 = mt * 64;
  int nw0 = (w & 1) * 32, hq = (w >> 1) * 4;

  // ---- x-side frags for all 4 heads: issue before staging (latency hidden)
  const unsigned short* xb = cv + ((size_t)b * NXX + n0 + nw0) * UU;
  bf16x8 afr[4][2][2];
#pragma unroll
  for (int hh = 0; hh < 4; hh++) {
    int co = (hq + hh) * 64;
#pragma unroll
    for (int tn = 0; tn < 2; tn++)
#pragma unroll
      for (int kb = 0; kb < 2; kb++)
        afr[hh][tn][kb] = *(const bf16x8*)(xb + (size_t)(tn * 16 + lane_m) * UU + co + kb * 32 + lane_g * 8);
  }

  // ---- stage y tile (64 rows x 512) into LDS, granule-XOR swizzle
  const unsigned short* yb = cv + ((size_t)(NB + b) * NYY + m0) * UU;
  {
    int seg = t & 63;
#pragma unroll
    for (int p = 0; p < 16; p++) {
      int r2 = p * 4 + (t >> 6);
      uint4 v = *(const uint4*)(yb + (size_t)r2 * UU + seg * 8);
      int sp = seg ^ (r2 & 7);
      *(uint4*)&ys[r2 * 512 + sp * 8] = v;
    }
  }

  // ---- mask -> mf16 (bf16 0/1) + count
  int is_u8 = det[0] != 0;
  unsigned int cl = 0;
  {
    int row = t >> 2, cq = (t & 3) * 16;
    size_t eb = ((size_t)b * NXX + n0 + row) * NYY + m0 + cq;
    if (is_u8) {
      uint4 v = *(const uint4*)((const unsigned char*)maskp + eb);
#pragma unroll
      for (int j = 0; j < 16; j++) {
        unsigned int word = ((const unsigned int*)&v)[j >> 2];
        int bit = ((word >> ((j & 3) * 8)) & 0xffu) != 0;
        mf16[row][cq + j] = bit ? 0x3F80u : 0u;
        cl += (unsigned)bit;
      }
    } else {
      const unsigned int* mp = (const unsigned int*)maskp + eb;
#pragma unroll
      for (int q = 0; q < 4; q++) {
        uint4 v = *(const uint4*)(mp + q * 4);
        unsigned int wds[4] = {v.x, v.y, v.z, v.w};
#pragma unroll
        for (int j = 0; j < 4; j++) {
          int bit = wds[j] != 0;
          mf16[row][cq + q * 4 + j] = bit ? 0x3F80u : 0u;
          cl += (unsigned)bit;
        }
      }
    }
  }
  for (int s = 1; s < 64; s <<= 1) cl += __shfl_xor(cl, s);
  if (l == 0) red[w][4] = (float)cl;
  __syncthreads();

  // ---- mask frags to regs (2-way LDS aliasing only)
  float mreg[2][4][4];
#pragma unroll
  for (int tn = 0; tn < 2; tn++)
#pragma unroll
    for (int tm = 0; tm < 4; tm++)
#pragma unroll
      for (int r = 0; r < 4; r++) {
        unsigned int u = (unsigned int)mf16[nw0 + tn * 16 + 4 * lane_g + r][tm * 16 + lane_m] << 16;
        union { unsigned int u; float f; } cvt; cvt.u = u;
        mreg[tn][tm][r] = cvt.f;
      }

  // ---- per-head: y frags from LDS, MFMA, fused relu*mask accumulate
  float hsv[4] = {0.f, 0.f, 0.f, 0.f};
#pragma unroll
  for (int hh = 0; hh < 4; hh++) {
    int segbase = (hq + hh) * 8;            // head chunk = 8 granules
    bf16x8 bfr[4][2];
#pragma unroll
    for (int tm = 0; tm < 4; tm++) {
      int row = tm * 16 + lane_m;
#pragma unroll
      for (int kb = 0; kb < 2; kb++) {
        int sp = (segbase + kb * 4 + lane_g) ^ (row & 7);
        bfr[tm][kb] = *(const bf16x8*)&ys[row * 512 + sp * 8];
      }
    }
#pragma unroll
    for (int tn = 0; tn < 2; tn++)
#pragma unroll
      for (int tm = 0; tm < 4; tm++) {
        f32x4 acc = {};
        acc = __builtin_amdgcn_mfma_f32_16x16x32_bf16(afr[hh][tn][0], bfr[tm][0], acc, 0, 0, 0);
        acc = __builtin_amdgcn_mfma_f32_16x16x32_bf16(afr[hh][tn][1], bfr[tm][1], acc, 0, 0, 0);
#pragma unroll
        for (int r = 0; r < 4; r++) {
          float v = acc[r];
          v = v > 0.f ? v : 0.f;
          hsv[hh] = fmaf(v, mreg[tn][tm][r], hsv[hh]);
        }
      }
  }
#pragma unroll
  for (int hh = 0; hh < 4; hh++) {
    float hs = hsv[hh];
    for (int s = 1; s < 64; s <<= 1) hs += __shfl_xor(hs, s);
    if (l == 0) red[w][hh] = hs;
  }
  __syncthreads();
  float* pb = part + (size_t)fl * 16;
  if (t < 8) {
    int q = t >> 2, hh = t & 3;
    pb[t] = red[q * 2][hh] + red[q * 2 + 1][hh];
  } else if (t == 8) {
    pb[8] = red[0][4] + red[1][4] + red[2][4] + red[3][4];
  }
}

// ---------------------------------------------------------------------------
// One block per b. Batch b's score blocks are fl = j*8 + b (fl&7==b), j=0..255.
__global__ __launch_bounds__(256) void finalize(
    const float* __restrict__ part, const float* __restrict__ fcw,
    const float* __restrict__ fcb, float* __restrict__ out) {
  __shared__ float red[4][9];
  int b = blockIdx.x;
  int t = threadIdx.x, w = t >> 6, l = t & 63;
  const float* pb = part + (size_t)(t * 8 + b) * 16;   // row fl = t*8+b
  float v[9];
#pragma unroll
  for (int j = 0; j < 9; j++) v[j] = pb[j];
#pragma unroll
  for (int j = 0; j < 9; j++) {
    float s = v[j];
    for (int ss = 1; ss < 64; ss <<= 1) s += __shfl_xor(s, ss);
    v[j] = s;
  }
  if (l == 0)
#pragma unroll
    for (int j = 0; j < 9; j++) red[w][j] = v[j];
  __syncthreads();
  if (t == 0) {
    float s = 0.f, cn = 0.f;
#pragma unroll
    for (int h = 0; h < NHEAD; h++)
      s += (red[0][h] + red[1][h] + red[2][h] + red[3][h]) * fcw[h];
    cn = red[0][8] + red[1][8] + red[2][8] + red[3][8];
    if (cn < 0.5f) cn = 1.f;
    out[b] = s * (SCALE_F / cn) + fcb[0];
  }
}

// ---------------------------------------------------------------------------
extern "C" void kernel_launch(void* const* d_in, const int* in_sizes, int n_in,
                              void* d_out, int out_size, void* d_ws, size_t ws_size,
                              hipStream_t stream) {
  const float* x = (const float*)d_in[0];
  const float* y = (const float*)d_in[1];
  const void* mask = d_in[2];
  const float* W = (const float*)d_in[3];
  const float* fcw = (const float*)d_in[4];
  const float* fcb = (const float*)d_in[5];
  float* out = (float*)d_out;
  char* ws = (char*)d_ws;

  unsigned short* cv = (unsigned short*)ws;                  // [16][1024][512] bf16 = 16 MB
  unsigned short* Wp = (unsigned short*)(ws + (16u << 20));  // packed W bf16 = 512 KB
  float* part = (float*)(ws + (16u << 20) + (1u << 19));     // [2048][16] f32 = 128 KB
  char* st = ws + (16u << 20) + (1u << 19) + (1u << 17);
  int* det = (int*)st;                                        // 1 i32

  hipMemsetAsync(st, 0, 64, stream);
  prep_kernel<<<144, 256, 0, stream>>>(W, Wp, (const unsigned char*)mask, det);
  conv_fused<<<512, 256, 0, stream>>>(x, y, Wp, cv);
  score_kernel<<<2048, 256, 0, stream>>>(cv, mask, det, part);
  finalize<<<NB, 256, 0, stream>>>(part, fcw, fcb, out);
}

// Round 9
// 142.485 us; speedup vs baseline: 1.4626x; 1.0126x over previous
//
#include <hip/hip_runtime.h>
#include <stdint.h>

#define UU 512
#define NHEAD 8
#define NB 8
#define NXX 1024
#define NYY 1024
#define SCALE_F 0.125f   // 1/sqrt(64)

typedef __bf16 bf16x8 __attribute__((ext_vector_type(8)));
typedef float f32x4 __attribute__((ext_vector_type(4)));
typedef unsigned short us4 __attribute__((ext_vector_type(4)));

__device__ __forceinline__ unsigned short f2bf(float f) {
  union { float f; uint32_t u; } v; v.f = f;
  return (unsigned short)((v.u + 0x7FFFu + ((v.u >> 16) & 1u)) >> 16);
}

// ---------------------------------------------------------------------------
// prep: blocks 0..127 pack W -> bf16 fragment-order Wp[ub][kb][lane][8]:
//   slot s = (ub*16+kb)*64 + l ; u = ub*16 + (l&15) ; k = kb*32 + (l>>4)*8.
// Blocks 128..143: mask dtype probe (u8 bool -> nonzero bytes at p%4==1).
__global__ void prep_kernel(const float* __restrict__ W, unsigned short* __restrict__ Wp,
                            const unsigned char* __restrict__ m, int* __restrict__ det) {
  int blk = blockIdx.x, t = threadIdx.x;
  if (blk < 128) {
    int s = blk * 256 + t;
    int ub = s >> 10, kb = (s >> 6) & 15, l = s & 63;
    int u = ub * 16 + (l & 15), k = kb * 32 + (l >> 4) * 8;
    const float* src = W + (size_t)u * UU + k;
    float4 a = *(const float4*)src;
    float4 bq = *(const float4*)(src + 4);
    uint4 o;
    o.x = (unsigned)f2bf(a.x) | ((unsigned)f2bf(a.y) << 16);
    o.y = (unsigned)f2bf(a.z) | ((unsigned)f2bf(a.w) << 16);
    o.z = (unsigned)f2bf(bq.x) | ((unsigned)f2bf(bq.y) << 16);
    o.w = (unsigned)f2bf(bq.z) | ((unsigned)f2bf(bq.w) << 16);
    *(uint4*)(Wp + (size_t)s * 8) = o;
  } else {
    int idx = ((blk - 128) * 256 + t) * 16;   // 16 blocks x 256 x 16B = 64KB
    uint4 v = *(const uint4*)(m + idx);
    unsigned int c1 = (v.x & 0xff00u) | (v.y & 0xff00u) | (v.z & 0xff00u) | (v.w & 0xff00u);
    if (c1) atomicOr(&det[0], 1);
  }
}

// ---------------------------------------------------------------------------
// cv -> pc in MFMA-FRAGMENT-PACKED layout:
//   pc[bz][q16][h][kb][lane][8], slot = ((bz*64 + q16)*8 + h)*2 + kb (512 sh).
//   lane = g*16 + lm encodes row = q16*16+lm, k = h*64 + kb*32 + g*8 + e.
// Conv block = (bz, 64 n-rows, 256 u = 4 heads, wave w owns head ut*4+w).
// x staged K-resident in LDS (transposed bf16, granule-XOR swizzle), no inner
// barriers; W frags from packed Wp (contiguous 1KB wave-loads).
__global__ __launch_bounds__(256, 2) void conv_fused(
    const float* __restrict__ x, const float* __restrict__ y,
    const unsigned short* __restrict__ Wp, unsigned short* __restrict__ pc) {
  __shared__ unsigned short xs[64 * 512];    // 64 KB
  int fl = blockIdx.x;
  int bz = fl & 15, nt = (fl >> 4) & 15, ut = fl >> 8;
  int b = bz & 7;
  const float* src = (bz >> 3) ? y : x;
  int n0 = nt * 64;
  int t = threadIdx.x, w = t >> 6, l = t & 63;
  int lane_m = l & 15, lane_g = l >> 4;

  // ---- stage x: [64n][512k] bf16, pair-packed along k, granule swizzle
  {
    int cq = (t & 15) * 4;
    int i2b = (t >> 4) * 2;
    const float* gb = src + (size_t)b * UU * NXX + n0 + cq;
#pragma unroll
    for (int it = 0; it < 16; it++) {
      int i2 = i2b + it * 32;
      float4 va = *(const float4*)(gb + (size_t)i2 * NXX);
      float4 vb = *(const float4*)(gb + (size_t)(i2 + 1) * NXX);
      float fa[4] = {va.x, va.y, va.z, va.w};
      float fb[4] = {vb.x, vb.y, vb.z, vb.w};
#pragma unroll
      for (int j = 0; j < 4; j++) {
        int n = cq + j;
        unsigned int pk = (unsigned)f2bf(fa[j]) | ((unsigned)f2bf(fb[j]) << 16);
        int e = n * 512 + (i2 ^ ((n & 7) << 3));
        *(unsigned int*)&xs[e] = pk;
      }
    }
  }
  __syncthreads();

  int u0 = ut * 256 + w * 64;
  int ub0 = u0 >> 4;                         // 16-row u-tile index base
  const unsigned short* wb0 = Wp + (size_t)l * 8;
  f32x4 acc[4][4] = {};
  bf16x8 aA[4], aB[4], bA[4], bB[4];

#define LOADW(Adst, Bdst, KB) do {                                            \
    _Pragma("unroll") for (int tu = 0; tu < 4; tu++)                          \
      Adst[tu] = *(const bf16x8*)(wb0 + ((size_t)(ub0 + tu) * 16 + (KB)) * 512); \
    _Pragma("unroll") for (int tn = 0; tn < 4; tn++) {                        \
      int nl_ = tn * 16 + lane_m;                                             \
      int ka_ = (KB) * 32 + lane_g * 8;                                       \
      Bdst[tn] = *(const bf16x8*)&xs[nl_ * 512 + (ka_ ^ ((nl_ & 7) << 3))];   \
    }                                                                         \
  } while (0)
#define DOMFMA(Ab, Bb) do {                                                   \
    _Pragma("unroll") for (int tn = 0; tn < 4; tn++)                          \
    _Pragma("unroll") for (int tu = 0; tu < 4; tu++)                          \
      acc[tn][tu] = __builtin_amdgcn_mfma_f32_16x16x32_bf16(Ab[tu], Bb[tn], acc[tn][tu], 0, 0, 0); \
  } while (0)

  LOADW(aA, bA, 0);
#pragma unroll
  for (int kp = 0; kp < 8; kp++) {
    LOADW(aB, bB, 2 * kp + 1);
    DOMFMA(aA, bA);
    if (kp < 7) LOADW(aA, bA, 2 * kp + 2);
    DOMFMA(aB, bB);
  }
#undef LOADW
#undef DOMFMA

  // ---- epilogue: write fragment-packed. h = u0>>6 (one head per wave).
  // off = tu*16+4*lane_g+r  ->  kb = tu>>1, g = (2tu+(lane_g>>1))&3,
  // e = 4*(lane_g&1)+r  (verified: kb*32+g*8+e == off).
  unsigned short* ob = pc + (size_t)bz * 64 * 8 * 2 * 512;
  int h = u0 >> 6;
  int e0 = 4 * (lane_g & 1);
#pragma unroll
  for (int tn = 0; tn < 4; tn++)
#pragma unroll
    for (int tu = 0; tu < 4; tu++) {
      int q16 = nt * 4 + tn;
      int kb = tu >> 1;
      int g = (2 * tu + (lane_g >> 1)) & 3;
      size_t slot = ((size_t)q16 * 8 + h) * 2 + kb;
      us4 pk;
      pk.x = f2bf(acc[tn][tu][0]); pk.y = f2bf(acc[tn][tu][1]);
      pk.z = f2bf(acc[tn][tu][2]); pk.w = f2bf(acc[tn][tu][3]);
      *(us4*)(ob + slot * 512 + (g * 16 + lane_m) * 8 + e0) = pk;
    }
}

// ---------------------------------------------------------------------------
// Block: (b, 64n, 64m), all 8 heads, 4 waves; wave: n-half (w&1), head-quad
// (w>>1). ALL A/B fragments are contiguous 1KB wave-loads from packed pc —
// no y staging, only mask goes through LDS. One barrier total.
__global__ __launch_bounds__(256, 3) void score_kernel(
    const unsigned short* __restrict__ pc, const void* __restrict__ maskp,
    const int* __restrict__ det, float* __restrict__ part) {
  __shared__ unsigned short mf16[64][72];    // 9.2 KB bf16 0/1
  __shared__ float red[4][8];
  int fl = blockIdx.x;
  int b = fl & 7, rr = fl >> 3;
  int nt = rr & 15, mt = rr >> 4;
  int t = threadIdx.x, w = t >> 6, l = t & 63;
  int lane_m = l & 15, lane_g = l >> 4;
  int n0 = nt * 64, m0 = mt * 64;
  int nw0 = (w & 1) * 32, hq = (w >> 1) * 4;

  // ---- mask -> mf16 (bf16 0/1) + count
  int is_u8 = det[0] != 0;
  unsigned int cl = 0;
  {
    int row = t >> 2, cq = (t & 3) * 16;
    size_t eb = ((size_t)b * NXX + n0 + row) * NYY + m0 + cq;
    if (is_u8) {
      uint4 v = *(const uint4*)((const unsigned char*)maskp + eb);
#pragma unroll
      for (int j = 0; j < 16; j++) {
        unsigned int word = ((const unsigned int*)&v)[j >> 2];
        int bit = ((word >> ((j & 3) * 8)) & 0xffu) != 0;
        mf16[row][cq + j] = bit ? 0x3F80u : 0u;
        cl += (unsigned)bit;
      }
    } else {
      const unsigned int* mp = (const unsigned int*)maskp + eb;
#pragma unroll
      for (int q = 0; q < 4; q++) {
        uint4 v = *(const uint4*)(mp + q * 4);
        unsigned int wds[4] = {v.x, v.y, v.z, v.w};
#pragma unroll
        for (int j = 0; j < 4; j++) {
          int bit = wds[j] != 0;
          mf16[row][cq + q * 4 + j] = bit ? 0x3F80u : 0u;
          cl += (unsigned)bit;
        }
      }
    }
  }
  for (int s = 1; s < 64; s <<= 1) cl += __shfl_xor(cl, s);
  if (l == 0) red[w][4] = (float)cl;
  __syncthreads();

  // ---- mask frags to regs (2-way LDS aliasing only)
  float mreg[2][4][4];
#pragma unroll
  for (int tn = 0; tn < 2; tn++)
#pragma unroll
    for (int tm = 0; tm < 4; tm++)
#pragma unroll
      for (int r = 0; r < 4; r++) {
        unsigned int u = (unsigned int)mf16[nw0 + tn * 16 + 4 * lane_g + r][tm * 16 + lane_m] << 16;
        union { unsigned int u; float f; } cvt; cvt.u = u;
        mreg[tn][tm][r] = cvt.f;
      }

  // ---- per-head: A/B frags as contiguous wave-loads, MFMA, relu*mask acc
  int xq0 = (n0 + nw0) >> 4;                 // x-side q16 base (2 tiles)
  int yq0 = m0 >> 4;                         // y-side q16 base (4 tiles)
  const unsigned short* xpl = pc + ((size_t)b * 64) * 8 * 2 * 512 + (size_t)l * 8;
  const unsigned short* ypl = pc + ((size_t)(NB + b) * 64) * 8 * 2 * 512 + (size_t)l * 8;
  float hsv[4] = {0.f, 0.f, 0.f, 0.f};
#pragma unroll
  for (int hh = 0; hh < 4; hh++) {
    int h = hq + hh;
    bf16x8 afr[2][2], bfr[4][2];
#pragma unroll
    for (int tn = 0; tn < 2; tn++)
#pragma unroll
      for (int kb = 0; kb < 2; kb++)
        afr[tn][kb] = *(const bf16x8*)(xpl + ((((size_t)(xq0 + tn)) * 8 + h) * 2 + kb) * 512);
#pragma unroll
    for (int tm = 0; tm < 4; tm++)
#pragma unroll
      for (int kb = 0; kb < 2; kb++)
        bfr[tm][kb] = *(const bf16x8*)(ypl + ((((size_t)(yq0 + tm)) * 8 + h) * 2 + kb) * 512);
#pragma unroll
    for (int tn = 0; tn < 2; tn++)
#pragma unroll
      for (int tm = 0; tm < 4; tm++) {
        f32x4 acc = {};
        acc = __builtin_amdgcn_mfma_f32_16x16x32_bf16(afr[tn][0], bfr[tm][0], acc, 0, 0, 0);
        acc = __builtin_amdgcn_mfma_f32_16x16x32_bf16(afr[tn][1], bfr[tm][1], acc, 0, 0, 0);
#pragma unroll
        for (int r = 0; r < 4; r++) {
          float v = acc[r];
          v = v > 0.f ? v : 0.f;
          hsv[hh] = fmaf(v, mreg[tn][tm][r], hsv[hh]);
        }
      }
  }
#pragma unroll
  for (int hh = 0; hh < 4; hh++) {
    float hs = hsv[hh];
    for (int s = 1; s < 64; s <<= 1) hs += __shfl_xor(hs, s);
    if (l == 0) red[w][hh] = hs;
  }
  __syncthreads();
  float* pb = part + (size_t)fl * 16;
  if (t < 8) {
    int q = t >> 2, hh = t & 3;
    pb[t] = red[q * 2][hh] + red[q * 2 + 1][hh];
  } else if (t == 8) {
    pb[8] = red[0][4] + red[1][4] + red[2][4] + red[3][4];
  }
}

// ---------------------------------------------------------------------------
// One block per b. Batch b's score blocks are fl = j*8 + b (fl&7==b), j=0..255.
__global__ __launch_bounds__(256) void finalize(
    const float* __restrict__ part, const float* __restrict__ fcw,
    const float* __restrict__ fcb, float* __restrict__ out) {
  __shared__ float red[4][9];
  int b = blockIdx.x;
  int t = threadIdx.x, w = t >> 6, l = t & 63;
  const float* pb = part + (size_t)(t * 8 + b) * 16;   // row fl = t*8+b
  float v[9];
#pragma unroll
  for (int j = 0; j < 9; j++) v[j] = pb[j];
#pragma unroll
  for (int j = 0; j < 9; j++) {
    float s = v[j];
    for (int ss = 1; ss < 64; ss <<= 1) s += __shfl_xor(s, ss);
    v[j] = s;
  }
  if (l == 0)
#pragma unroll
    for (int j = 0; j < 9; j++) red[w][j] = v[j];
  __syncthreads();
  if (t == 0) {
    float s = 0.f, cn = 0.f;
#pragma unroll
    for (int h = 0; h < NHEAD; h++)
      s += (red[0][h] + red[1][h] + red[2][h] + red[3][h]) * fcw[h];
    cn = red[0][8] + red[1][8] + red[2][8] + red[3][8];
    if (cn < 0.5f) cn = 1.f;
    out[b] = s * (SCALE_F / cn) + fcb[0];
  }
}

// ---------------------------------------------------------------------------
extern "C" void kernel_launch(void* const* d_in, const int* in_sizes, int n_in,
                              void* d_out, int out_size, void* d_ws, size_t ws_size,
                              hipStream_t stream) {
  const float* x = (const float*)d_in[0];
  const float* y = (const float*)d_in[1];
  const void* mask = d_in[2];
  const float* W = (const float*)d_in[3];
  const float* fcw = (const float*)d_in[4];
  const float* fcb = (const float*)d_in[5];
  float* out = (float*)d_out;
  char* ws = (char*)d_ws;

  unsigned short* pc = (unsigned short*)ws;                  // packed conv out, 16 MB
  unsigned short* Wp = (unsigned short*)(ws + (16u << 20));  // packed W bf16 = 512 KB
  float* part = (float*)(ws + (16u << 20) + (1u << 19));     // [2048][16] f32 = 128 KB
  char* st = ws + (16u << 20) + (1u << 19) + (1u << 17);
  int* det = (int*)st;                                        // 1 i32

  hipMemsetAsync(st, 0, 64, stream);
  prep_kernel<<<144, 256, 0, stream>>>(W, Wp, (const unsigned char*)mask, det);
  conv_fused<<<512, 256, 0, stream>>>(x, y, Wp, pc);
  score_kernel<<<2048, 256, 0, stream>>>(pc, mask, det, part);
  finalize<<<NB, 256, 0, stream>>>(part, fcw, fcb, out);
}